// Round 17
// baseline (561.374 us; speedup 1.0000x reference)
//
#include <hip/hip_runtime.h>
#include <hip/hip_cooperative_groups.h>

namespace cg = cooperative_groups;

#define N_NODES  100000
#define N_EDGES  1600000
#define N_GRAPHS 256
#define F        64

#define CHUNK    8192
#define NCHUNK   196        // ceil(N_EDGES / CHUNK)
#define GBN      128        // nodes per bucket
#define NB2      782        // ceil(N_NODES / GBN)
#define EDGE_CAP 2560       // per-bucket edge cap (mean 2048, +11 sigma)

#define CAST_ELEMS (N_NODES * F / 4)        // 1,600,000 float4
#define NCHK16     ((N_NODES + 15) / 16)    // 6250 16-node gather tasks

__device__ __forceinline__ unsigned short f2bf(float f) {
    unsigned int u = __float_as_uint(f);
    u += 0x7FFFu + ((u >> 16) & 1u);
    return (unsigned short)(u >> 16);
}
__device__ __forceinline__ float bfl(unsigned int u) { return __uint_as_float(u << 16); }
__device__ __forceinline__ float bfh(unsigned int u) { return __uint_as_float(u & 0xFFFF0000u); }

union PhaseLDS {
    struct {                       // prep: 43,124 B
        int hist[NB2];
        int cur[NB2];
        int scan[1024];
        unsigned int stage[CHUNK];
    } p;
    struct {                       // compact: 13,860 B
        int rstart[NCHUNK];
        int roff[NCHUNK + 1];
        int sc[256];
        unsigned int epairs[EDGE_CAP];
        int ncnt[GBN];
        int ncur[GBN];
    } c;
};

__global__ __launch_bounds__(1024) void mega_kernel(
        const float* __restrict__ x,
        unsigned short* __restrict__ xh,
        const int* __restrict__ src, const int* __restrict__ dst,
        unsigned int* __restrict__ pairs, int* __restrict__ cstartT,
        int* __restrict__ eidx, int* __restrict__ nbeg, int* __restrict__ nend,
        const int* __restrict__ batch,
        const float* __restrict__ Wg, const float* __restrict__ bg,
        const float* __restrict__ Wa, const float* __restrict__ ba,
        float* __restrict__ out, float* __restrict__ denom) {
    cg::grid_group grid = cg::this_grid();
    __shared__ PhaseLDS sh;
    int tid = threadIdx.x;
    int nB  = gridDim.x;

    // ================= PHASE P: zero-init + cast + chunk-local bucket sort ==========
    for (int c = blockIdx.x; c < NCHUNK; c += nB) {
        int base = c * CHUNK;
        int m    = min(CHUNK, N_EDGES - base);
        for (int k = tid; k < NB2; k += 1024) sh.p.hist[k] = 0;
        __syncthreads();
        for (int e = tid; e < m; e += 1024)
            atomicAdd(&sh.p.hist[dst[base + e] >> 7], 1);
        __syncthreads();
        sh.p.scan[tid] = (tid < NB2) ? sh.p.hist[tid] : 0;
        __syncthreads();
        #pragma unroll
        for (int o = 1; o < 1024; o <<= 1) {
            int u = (tid >= o) ? sh.p.scan[tid - o] : 0;
            __syncthreads();
            sh.p.scan[tid] += u;
            __syncthreads();
        }
        if (tid < NB2) {
            int excl = sh.p.scan[tid] - sh.p.hist[tid];
            sh.p.cur[tid] = excl;
            cstartT[tid * NCHUNK + c] = base + excl;
        }
        if (tid == 0) cstartT[NB2 * NCHUNK + c] = base + m;   // sentinel row
        __syncthreads();
        for (int e = tid; e < m; e += 1024) {
            int d = dst[base + e];
            int slot = atomicAdd(&sh.p.cur[d >> 7], 1);
            sh.p.stage[slot] = ((unsigned)(d & (GBN - 1)) << 17) | (unsigned)src[base + e];
        }
        __syncthreads();
        for (int e = tid; e < m; e += 1024)
            pairs[base + e] = sh.p.stage[e];                  // fully coalesced
        __syncthreads();
    }
    if (blockIdx.x >= NCHUNK) {
        int castBlocks = nB - NCHUNK;
        int ci = blockIdx.x - NCHUNK;
        if (ci == 0) {
            for (int i = tid; i < N_GRAPHS * F; i += 1024) out[i] = 0.f;
            if (tid < N_GRAPHS) denom[tid] = 0.f;
        }
        for (int i = ci * 1024 + tid; i < CAST_ELEMS; i += castBlocks * 1024) {
            float4 v = ((const float4*)x)[i];
            ushort4 o;
            o.x = f2bf(v.x); o.y = f2bf(v.y); o.z = f2bf(v.z); o.w = f2bf(v.w);
            ((ushort4*)xh)[i] = o;
        }
    }
    __threadfence();
    grid.sync();

    // ================= PHASE C: per-bucket compact -> node-grouped eidx =============
    for (int b = blockIdx.x; b < NB2; b += nB) {
        int node0 = b * GBN;
        int nn    = min(GBN, N_NODES - node0);
        int gbase = b * EDGE_CAP;

        int myrc = 0;
        if (tid < NCHUNK) {
            int a = cstartT[b * NCHUNK + tid];          // coalesced row
            int n = cstartT[(b + 1) * NCHUNK + tid];
            sh.c.rstart[tid] = a;
            myrc = n - a;
        }
        __syncthreads();
        if (tid < 256) sh.c.sc[tid] = (tid < NCHUNK) ? myrc : 0;
        __syncthreads();
        #pragma unroll
        for (int o = 1; o < 256; o <<= 1) {
            int u = (tid < 256 && tid >= o) ? sh.c.sc[tid - o] : 0;
            __syncthreads();
            if (tid < 256) sh.c.sc[tid] += u;
            __syncthreads();
        }
        if (tid < NCHUNK) sh.c.roff[tid] = sh.c.sc[tid] - myrc;
        if (tid == 0) sh.c.roff[NCHUNK] = sh.c.sc[NCHUNK - 1];
        __syncthreads();
        int E = sh.c.roff[NCHUNK];

        for (int e = tid; e < E; e += 1024) {           // binary-search run copy
            int lo = 0, hi = NCHUNK - 1;
            while (lo < hi) {
                int mid = (lo + hi + 1) >> 1;
                if (sh.c.roff[mid] <= e) lo = mid; else hi = mid - 1;
            }
            sh.c.epairs[e] = pairs[sh.c.rstart[lo] + (e - sh.c.roff[lo])];
        }
        __syncthreads();
        if (tid < GBN) sh.c.ncnt[tid] = 0;
        __syncthreads();
        for (int e = tid; e < E; e += 1024)
            atomicAdd(&sh.c.ncnt[sh.c.epairs[e] >> 17], 1);
        __syncthreads();
        if (tid < 128) sh.c.sc[tid] = sh.c.ncnt[tid];
        __syncthreads();
        #pragma unroll
        for (int o = 1; o < 128; o <<= 1) {
            int u = (tid < 128 && tid >= o) ? sh.c.sc[tid - o] : 0;
            __syncthreads();
            if (tid < 128) sh.c.sc[tid] += u;
            __syncthreads();
        }
        if (tid < GBN) {
            int excl = sh.c.sc[tid] - sh.c.ncnt[tid];
            sh.c.ncur[tid] = excl;
            if (tid < nn) {
                nbeg[node0 + tid] = gbase + excl;
                nend[node0 + tid] = gbase + excl + sh.c.ncnt[tid];
            }
        }
        __syncthreads();
        for (int e = tid; e < E; e += 1024) {
            unsigned int p = sh.c.epairs[e];
            int slot = atomicAdd(&sh.c.ncur[p >> 17], 1);
            eidx[gbase + slot] = (int)(p & 0x1FFFFu);
        }
        __syncthreads();
    }
    __threadfence();
    grid.sync();

    // ================= PHASE G: fused gather(bf16)+transform+pool ===================
    {
        int lane = tid & 63;
        int grp  = lane >> 3;
        int c    = lane & 7;
        int waveId     = blockIdx.x * 16 + (tid >> 6);
        int totalWaves = nB * 16;

        float bgl = bg[lane];
        float wal = Wa[lane];
        float ba0 = ba[0];
        float wcol[F];
        #pragma unroll
        for (int k = 0; k < F; ++k) wcol[k] = Wg[k * F + lane];

        const uint4* xh4 = (const uint4*)xh;

        for (int t = waveId; t < NCHK16; t += totalWaves) {
            int n0   = t * 16;
            int nEnd = min(n0 + 16, N_NODES);

            int   cur_g = batch[n0];
            float accw  = 0.f;
            float denw  = 0.f;

            int pb = nbeg[n0];
            int pe = nend[n0];
            int sl_cur = (pb + lane < pe) ? eidx[pb + lane] : 0;

            for (int n = n0; n < nEnd; ++n) {
                int start = pb, end = pe;
                int sl    = sl_cur;
                if (n + 1 < nEnd) {
                    pb = nbeg[n + 1];
                    pe = nend[n + 1];
                    sl_cur = (pb + lane < pe) ? eidx[pb + lane] : 0;
                }

                float a0=0.f,a1=0.f,a2=0.f,a3=0.f,a4=0.f,a5=0.f,a6=0.f,a7=0.f;
                {
                    int jmax = end - start; if (jmax > 64) jmax = 64;
                    for (int j = 0; j < jmax; j += 8) {
                        int el = j + grp;
                        int s  = __shfl(sl, el, 64);
                        if (el < jmax) {
                            uint4 v = xh4[s * 8 + c];
                            a0 += bfl(v.x); a1 += bfh(v.x);
                            a2 += bfl(v.y); a3 += bfh(v.y);
                            a4 += bfl(v.z); a5 += bfh(v.z);
                            a6 += bfl(v.w); a7 += bfh(v.w);
                        }
                    }
                }
                for (int base = start + 64; base < end; base += 64) {
                    int jmax = end - base; if (jmax > 64) jmax = 64;
                    int sl2 = (base + lane < end) ? eidx[base + lane] : 0;
                    for (int j = 0; j < jmax; j += 8) {
                        int el = j + grp;
                        int s  = __shfl(sl2, el, 64);
                        if (el < jmax) {
                            uint4 v = xh4[s * 8 + c];
                            a0 += bfl(v.x); a1 += bfh(v.x);
                            a2 += bfl(v.y); a3 += bfh(v.y);
                            a4 += bfl(v.z); a5 += bfh(v.z);
                            a6 += bfl(v.w); a7 += bfh(v.w);
                        }
                    }
                }
                #pragma unroll
                for (int o = 8; o <= 32; o <<= 1) {
                    a0 += __shfl_xor(a0, o, 64); a1 += __shfl_xor(a1, o, 64);
                    a2 += __shfl_xor(a2, o, 64); a3 += __shfl_xor(a3, o, 64);
                    a4 += __shfl_xor(a4, o, 64); a5 += __shfl_xor(a5, o, 64);
                    a6 += __shfl_xor(a6, o, 64); a7 += __shfl_xor(a7, o, 64);
                }
                {
                    uint4 v = xh4[n * 8 + c];   // self row
                    a0 += bfl(v.x); a1 += bfh(v.x);
                    a2 += bfl(v.y); a3 += bfh(v.y);
                    a4 += bfl(v.z); a5 += bfh(v.z);
                    a6 += bfl(v.w); a7 += bfh(v.w);
                }

                float re[8] = {a0,a1,a2,a3,a4,a5,a6,a7};
                float q0=0.f,q1=0.f,q2=0.f,q3=0.f,q4=0.f,q5=0.f,q6=0.f,q7=0.f;
                #pragma unroll
                for (int k = 0; k < F; k += 8) {
                    int ln = k >> 3;
                    q0 += __int_as_float(__builtin_amdgcn_readlane(__float_as_int(re[0]), ln)) * wcol[k + 0];
                    q1 += __int_as_float(__builtin_amdgcn_readlane(__float_as_int(re[1]), ln)) * wcol[k + 1];
                    q2 += __int_as_float(__builtin_amdgcn_readlane(__float_as_int(re[2]), ln)) * wcol[k + 2];
                    q3 += __int_as_float(__builtin_amdgcn_readlane(__float_as_int(re[3]), ln)) * wcol[k + 3];
                    q4 += __int_as_float(__builtin_amdgcn_readlane(__float_as_int(re[4]), ln)) * wcol[k + 4];
                    q5 += __int_as_float(__builtin_amdgcn_readlane(__float_as_int(re[5]), ln)) * wcol[k + 5];
                    q6 += __int_as_float(__builtin_amdgcn_readlane(__float_as_int(re[6]), ln)) * wcol[k + 6];
                    q7 += __int_as_float(__builtin_amdgcn_readlane(__float_as_int(re[7]), ln)) * wcol[k + 7];
                }
                float hv = ((q0 + q1) + (q2 + q3)) + ((q4 + q5) + (q6 + q7)) + bgl;
                hv = hv > 0.f ? hv : 0.f;

                float p = hv * wal;
                #pragma unroll
                for (int o = 32; o > 0; o >>= 1)
                    p += __shfl_down(p, o, 64);
                float s = __int_as_float(__builtin_amdgcn_readlane(__float_as_int(p), 0)) + ba0;
                float e = __expf(s);

                int g = batch[n];
                if (g != cur_g) {
                    atomicAdd(&out[cur_g * F + lane], accw);
                    if (lane == 0) atomicAdd(&denom[cur_g], denw);
                    accw = 0.f; denw = 0.f; cur_g = g;
                }
                accw += e * hv;
                denw += e;
            }
            atomicAdd(&out[cur_g * F + lane], accw);
            if (lane == 0) atomicAdd(&denom[cur_g], denw);
        }
    }
    __threadfence();
    grid.sync();

    // ================= PHASE F: out /= denom ========================================
    for (int i = blockIdx.x * 1024 + tid; i < N_GRAPHS * F; i += nB * 1024) {
        float d = denom[i >> 6];
        out[i] = (d > 0.f) ? out[i] / d : 0.f;
    }
}

extern "C" void kernel_launch(void* const* d_in, const int* in_sizes, int n_in,
                              void* d_out, int out_size, void* d_ws, size_t ws_size,
                              hipStream_t stream) {
    const float* x     = (const float*)d_in[0];
    const int*   ei    = (const int*)d_in[1];   // [2, N_EDGES]
    const int*   batch = (const int*)d_in[2];   // [N_NODES]
    const float* Wg    = (const float*)d_in[3];
    const float* bg    = (const float*)d_in[4];
    const float* Wa    = (const float*)d_in[5];
    const float* ba    = (const float*)d_in[6];
    float* out = (float*)d_out;

    const int* src = ei;
    const int* dst = ei + N_EDGES;

    // workspace layout (bytes, 256-aligned)
    char* ws = (char*)d_ws;
    unsigned short* xh      = (unsigned short*)(ws);           // 12,800,000
    unsigned int*   pairs   = (unsigned int*)(ws + 12800000);  //  6,400,000
    int*            cstartT = (int*)(ws + 19200000);           //    613,872
    int*            eidx    = (int*)(ws + 19814144);           //  8,007,680
    int*            nbeg    = (int*)(ws + 27821824);           //    400,000
    int*            nend    = (int*)(ws + 28221824);           //    400,000
    float*          denom   = (float*)(ws + 28621824);         //      1,024

    // same result every call: occupancy query is deterministic
    int maxB = 0;
    hipOccupancyMaxActiveBlocksPerMultiprocessor(&maxB, mega_kernel, 1024, 0);
    if (maxB < 1) maxB = 1;
    int grid = maxB * 256;
    if (grid > 512) grid = 512;   // 512 blocks x 16 waves = plenty

    void* args[] = {
        (void*)&x, (void*)&xh, (void*)&src, (void*)&dst,
        (void*)&pairs, (void*)&cstartT, (void*)&eidx, (void*)&nbeg, (void*)&nend,
        (void*)&batch, (void*)&Wg, (void*)&bg, (void*)&Wa, (void*)&ba,
        (void*)&out, (void*)&denom
    };
    hipLaunchCooperativeKernel((void*)mega_kernel, dim3(grid), dim3(1024),
                               args, 0, stream);
}

// Round 18
// 189.411 us; speedup vs baseline: 2.9638x; 2.9638x over previous
//
#include <hip/hip_runtime.h>

#define N_NODES  100000
#define N_EDGES  1600000
#define N_GRAPHS 256
#define F        64

#define CHUNK    8192
#define NCHUNK   196        // ceil(N_EDGES / CHUNK); last chunk = 2560 edges
#define GBN      128        // nodes per bucket
#define NB2      782        // ceil(N_NODES / GBN)
#define EDGE_CAP 2560       // per-bucket edge cap (mean 2048, +11 sigma)

#define CAST_ELEMS   (N_NODES * F / 4)                  // 1,600,000 float4
#define CAST_BLOCKS  ((CAST_ELEMS + 1023) / 1024)       // 1563
#define PREP_BLOCKS  (NCHUNK + CAST_BLOCKS)             // 1759

__device__ __forceinline__ unsigned short f2bf(float f) {
    unsigned int u = __float_as_uint(f);
    u += 0x7FFFu + ((u >> 16) & 1u);
    return (unsigned short)(u >> 16);
}

// ---------- K1: fused prep = zero-init + cast(x->bf16) + chunk-local bucket sort ----------
__global__ __launch_bounds__(1024) void prep_kernel(
        const float* __restrict__ x, unsigned short* __restrict__ xh,
        const int* __restrict__ src, const int* __restrict__ dst,
        unsigned int* __restrict__ pairs, int* __restrict__ cstartT,
        float* __restrict__ out, float* __restrict__ denom) {
    int tid = threadIdx.x;
    int b   = blockIdx.x;

    if (b >= NCHUNK) {
        int ci = b - NCHUNK;
        if (ci == 0) {
            for (int i = tid; i < N_GRAPHS * F; i += 1024) out[i] = 0.f;
            if (tid < N_GRAPHS) denom[tid] = 0.f;
        }
        int i = ci * 1024 + tid;
        if (i < CAST_ELEMS) {
            float4 v = ((const float4*)x)[i];
            ushort4 o;
            o.x = f2bf(v.x); o.y = f2bf(v.y); o.z = f2bf(v.z); o.w = f2bf(v.w);
            ((ushort4*)xh)[i] = o;
        }
        return;
    }

    // ---- scatter_sort: chunk b owns pairs[b*CHUNK ..), bucket-ordered, coalesced ----
    __shared__ int hist[NB2];
    __shared__ int cur[NB2];
    __shared__ int wsum[16];
    __shared__ unsigned int stage[CHUNK];   // 32 KB
    int c    = b;
    int base = c * CHUNK;
    int m    = min(CHUNK, N_EDGES - base);
    int lane = tid & 63;
    int w    = tid >> 6;

    for (int k = tid; k < NB2; k += 1024) hist[k] = 0;
    __syncthreads();
    for (int e = tid; e < m; e += 1024)
        atomicAdd(&hist[dst[base + e] >> 7], 1);
    __syncthreads();

    // two-level inclusive scan of hist over 1024 threads (2 barriers)
    int v = (tid < NB2) ? hist[tid] : 0;
    #pragma unroll
    for (int o = 1; o < 64; o <<= 1) {
        int u = __shfl_up(v, o, 64);
        if (lane >= o) v += u;
    }
    if (lane == 63) wsum[w] = v;
    __syncthreads();
    if (tid < 16) {
        int s = wsum[tid];
        #pragma unroll
        for (int o = 1; o < 16; o <<= 1) {
            int u = __shfl_up(s, o, 64);
            if (tid >= o) s += u;
        }
        wsum[tid] = s;
    }
    __syncthreads();
    if (w > 0) v += wsum[w - 1];

    if (tid < NB2) {
        int excl = v - hist[tid];
        cur[tid] = excl;
        cstartT[tid * NCHUNK + c] = base + excl;
    }
    if (tid == 0) cstartT[NB2 * NCHUNK + c] = base + m;   // sentinel row
    __syncthreads();
    for (int e = tid; e < m; e += 1024) {
        int d = dst[base + e];
        int slot = atomicAdd(&cur[d >> 7], 1);
        stage[slot] = ((unsigned)(d & (GBN - 1)) << 17) | (unsigned)src[base + e];
    }
    __syncthreads();
    for (int e = tid; e < m; e += 1024)
        pairs[base + e] = stage[e];                       // fully coalesced
}

// ---------- K2: per-bucket compact -> node-grouped eidx (bucket-major, padded) ----------
__global__ __launch_bounds__(512) void compact_kernel(
        const unsigned int* __restrict__ pairs,
        const int* __restrict__ cstartT,
        int* __restrict__ eidx,     // [NB2 * EDGE_CAP]
        int* __restrict__ nbeg,     // [N_NODES]
        int* __restrict__ nend) {   // [N_NODES]
    __shared__ int rstart[NCHUNK];
    __shared__ int rcnt[NCHUNK];
    __shared__ int roff[NCHUNK];
    __shared__ int wsum[8];
    __shared__ int Etot_s;
    __shared__ unsigned int epairs[EDGE_CAP];   // 10 KB
    __shared__ int ncnt[GBN];
    __shared__ int ncur[GBN];

    int tid   = threadIdx.x;
    int wave  = tid >> 6;
    int lane  = tid & 63;
    int b     = blockIdx.x;
    int node0 = b * GBN;
    int nn    = min(GBN, N_NODES - node0);
    int gbase = b * EDGE_CAP;

    int myrc = 0;
    if (tid < NCHUNK) {
        int a = cstartT[b * NCHUNK + tid];          // coalesced row
        int n = cstartT[(b + 1) * NCHUNK + tid];
        rstart[tid] = a;
        rcnt[tid]   = n - a;
        myrc = n - a;
    }
    __syncthreads();

    // two-level inclusive scan of myrc over 512 threads (2 barriers)
    {
        int v = myrc;
        #pragma unroll
        for (int o = 1; o < 64; o <<= 1) {
            int u = __shfl_up(v, o, 64);
            if (lane >= o) v += u;
        }
        if (lane == 63) wsum[wave] = v;
        __syncthreads();
        if (tid < 8) {
            int s = wsum[tid];
            #pragma unroll
            for (int o = 1; o < 8; o <<= 1) {
                int u = __shfl_up(s, o, 64);
                if (tid >= o) s += u;
            }
            wsum[tid] = s;
        }
        __syncthreads();
        if (wave > 0) v += wsum[wave - 1];
        if (tid < NCHUNK) roff[tid] = v - myrc;
        if (tid == NCHUNK - 1) Etot_s = v;
    }
    __syncthreads();
    int E = Etot_s;

    // cooperative run copy (wave per run; run len ~10)
    for (int r = wave; r < NCHUNK; r += 8) {
        int cr = rcnt[r];
        for (int l = lane; l < cr; l += 64)
            epairs[roff[r] + l] = pairs[rstart[r] + l];
    }
    __syncthreads();

    // LDS counting sort by dstLocal -> eidx grouped per node
    if (tid < GBN) ncnt[tid] = 0;
    __syncthreads();
    for (int e = tid; e < E; e += 512)
        atomicAdd(&ncnt[epairs[e] >> 17], 1);
    __syncthreads();
    {
        int mycnt = (tid < GBN) ? ncnt[tid] : 0;
        int v = mycnt;
        #pragma unroll
        for (int o = 1; o < 64; o <<= 1) {
            int u = __shfl_up(v, o, 64);
            if (lane >= o) v += u;
        }
        if (lane == 63) wsum[wave] = v;
        __syncthreads();
        if (tid < 8) {
            int s = wsum[tid];
            #pragma unroll
            for (int o = 1; o < 8; o <<= 1) {
                int u = __shfl_up(s, o, 64);
                if (tid >= o) s += u;
            }
            wsum[tid] = s;
        }
        __syncthreads();
        if (wave > 0) v += wsum[wave - 1];
        if (tid < GBN) {
            int excl = v - mycnt;
            ncur[tid] = excl;
            if (tid < nn) {
                nbeg[node0 + tid] = gbase + excl;
                nend[node0 + tid] = gbase + excl + mycnt;
            }
        }
    }
    __syncthreads();
    for (int e = tid; e < E; e += 512) {
        unsigned int p = epairs[e];
        int slot = atomicAdd(&ncur[p >> 17], 1);
        eidx[gbase + slot] = (int)(p & 0x1FFFFu);   // random within 10 KB window
    }
}

// ---------- K3: fused gather(bf16)+transform+pool (R14-proven body, untouched) ----------
#define NODES_PER_WAVE 25
#define GT_NWAVES  (N_NODES / NODES_PER_WAVE)   // 4000
#define GT_BLOCKS  (GT_NWAVES / 4)              // 1000

__device__ __forceinline__ float bfl(unsigned int u) { return __uint_as_float(u << 16); }
__device__ __forceinline__ float bfh(unsigned int u) { return __uint_as_float(u & 0xFFFF0000u); }

__global__ __launch_bounds__(256) void gather_pool_kernel(
        const unsigned short* __restrict__ xh,
        const int*   __restrict__ nbeg,
        const int*   __restrict__ nend,
        const int*   __restrict__ eidx,
        const int*   __restrict__ batch,
        const float* __restrict__ Wg,   // [64,64] (k, f)
        const float* __restrict__ bg,
        const float* __restrict__ Wa,
        const float* __restrict__ ba,
        float*       __restrict__ out_acc,   // [N_GRAPHS, F]
        float*       __restrict__ denom) {  // [N_GRAPHS]
    int tid  = threadIdx.x;
    int lane = tid & 63;
    int grp  = lane >> 3;   // 0..7: row within an 8-row gather batch
    int c    = lane & 7;    // 16-B chunk (8 bf16) within a row
    int waveId = blockIdx.x * 4 + (tid >> 6);

    int n0   = waveId * NODES_PER_WAVE;     // grid exactly covers N_NODES
    int nEnd = n0 + NODES_PER_WAVE;

    float wcol[F];
    #pragma unroll
    for (int k = 0; k < F; ++k) wcol[k] = Wg[k * F + lane];
    float bgl = bg[lane];
    float wal = Wa[lane];
    float ba0 = ba[0];

    const uint4* xh4 = (const uint4*)xh;     // row = 8 uint4

    int   cur_g = batch[n0];
    float accw  = 0.f;   // per-lane: sum e * h[lane]
    float denw  = 0.f;   // replicated: sum e

    // prefetch state: first-chunk edge indices of the current node
    int pb = nbeg[n0];
    int pe = nend[n0];
    int sl_cur = (pb + lane < pe) ? eidx[pb + lane] : 0;

    for (int n = n0; n < nEnd; ++n) {
        int start = pb, end = pe;
        int sl    = sl_cur;
        if (n + 1 < nEnd) {     // prefetch node n+1 while n's gathers fly
            pb = nbeg[n + 1];
            pe = nend[n + 1];
            sl_cur = (pb + lane < pe) ? eidx[pb + lane] : 0;
        }

        float a0=0.f,a1=0.f,a2=0.f,a3=0.f,a4=0.f,a5=0.f,a6=0.f,a7=0.f;
        // first (almost always only) 64-edge chunk
        {
            int jmax = end - start; if (jmax > 64) jmax = 64;
            for (int j = 0; j < jmax; j += 8) {
                int el = j + grp;
                int s  = __shfl(sl, el, 64);
                if (el < jmax) {
                    uint4 v = xh4[s * 8 + c];   // 16 B/lane, 8 rows per instruction
                    a0 += bfl(v.x); a1 += bfh(v.x);
                    a2 += bfl(v.y); a3 += bfh(v.y);
                    a4 += bfl(v.z); a5 += bfh(v.z);
                    a6 += bfl(v.w); a7 += bfh(v.w);
                }
            }
        }
        // rare extra chunks (deg > 64)
        for (int base = start + 64; base < end; base += 64) {
            int jmax = end - base; if (jmax > 64) jmax = 64;
            int sl2 = (base + lane < end) ? eidx[base + lane] : 0;
            for (int j = 0; j < jmax; j += 8) {
                int el = j + grp;
                int s  = __shfl(sl2, el, 64);
                if (el < jmax) {
                    uint4 v = xh4[s * 8 + c];
                    a0 += bfl(v.x); a1 += bfh(v.x);
                    a2 += bfl(v.y); a3 += bfh(v.y);
                    a4 += bfl(v.z); a5 += bfh(v.z);
                    a6 += bfl(v.w); a7 += bfh(v.w);
                }
            }
        }
        #pragma unroll
        for (int o = 8; o <= 32; o <<= 1) {
            a0 += __shfl_xor(a0, o, 64); a1 += __shfl_xor(a1, o, 64);
            a2 += __shfl_xor(a2, o, 64); a3 += __shfl_xor(a3, o, 64);
            a4 += __shfl_xor(a4, o, 64); a5 += __shfl_xor(a5, o, 64);
            a6 += __shfl_xor(a6, o, 64); a7 += __shfl_xor(a7, o, 64);
        }
        {
            uint4 v = xh4[n * 8 + c];   // self row
            a0 += bfl(v.x); a1 += bfh(v.x);
            a2 += bfl(v.y); a3 += bfh(v.y);
            a4 += bfl(v.z); a5 += bfh(v.z);
            a6 += bfl(v.w); a7 += bfh(v.w);
        }

        float re[8] = {a0,a1,a2,a3,a4,a5,a6,a7};
        float q0=0.f,q1=0.f,q2=0.f,q3=0.f,q4=0.f,q5=0.f,q6=0.f,q7=0.f;
        #pragma unroll
        for (int k = 0; k < F; k += 8) {
            int ln = k >> 3;
            q0 += __int_as_float(__builtin_amdgcn_readlane(__float_as_int(re[0]), ln)) * wcol[k + 0];
            q1 += __int_as_float(__builtin_amdgcn_readlane(__float_as_int(re[1]), ln)) * wcol[k + 1];
            q2 += __int_as_float(__builtin_amdgcn_readlane(__float_as_int(re[2]), ln)) * wcol[k + 2];
            q3 += __int_as_float(__builtin_amdgcn_readlane(__float_as_int(re[3]), ln)) * wcol[k + 3];
            q4 += __int_as_float(__builtin_amdgcn_readlane(__float_as_int(re[4]), ln)) * wcol[k + 4];
            q5 += __int_as_float(__builtin_amdgcn_readlane(__float_as_int(re[5]), ln)) * wcol[k + 5];
            q6 += __int_as_float(__builtin_amdgcn_readlane(__float_as_int(re[6]), ln)) * wcol[k + 6];
            q7 += __int_as_float(__builtin_amdgcn_readlane(__float_as_int(re[7]), ln)) * wcol[k + 7];
        }
        float hv = ((q0 + q1) + (q2 + q3)) + ((q4 + q5) + (q6 + q7)) + bgl;
        hv = hv > 0.f ? hv : 0.f;

        float p = hv * wal;
        #pragma unroll
        for (int o = 32; o > 0; o >>= 1)
            p += __shfl_down(p, o, 64);
        float s = __int_as_float(__builtin_amdgcn_readlane(__float_as_int(p), 0)) + ba0;
        float e = __expf(s);    // unshifted: softmax ratio is shift-invariant

        int g = batch[n];       // wave-uniform
        if (g != cur_g) {
            atomicAdd(&out_acc[cur_g * F + lane], accw);
            if (lane == 0) atomicAdd(&denom[cur_g], denw);
            accw = 0.f; denw = 0.f; cur_g = g;
        }
        accw += e * hv;
        denw += e;
    }
    atomicAdd(&out_acc[cur_g * F + lane], accw);
    if (lane == 0) atomicAdd(&denom[cur_g], denw);
}

// ---------- K4: out /= denom ----------
__global__ __launch_bounds__(256) void finalize_kernel(
        float* __restrict__ out, const float* __restrict__ denom) {
    int i = blockIdx.x * 256 + threadIdx.x;
    if (i >= N_GRAPHS * F) return;
    float d = denom[i >> 6];
    out[i] = (d > 0.f) ? out[i] / d : 0.f;
}

extern "C" void kernel_launch(void* const* d_in, const int* in_sizes, int n_in,
                              void* d_out, int out_size, void* d_ws, size_t ws_size,
                              hipStream_t stream) {
    const float* x     = (const float*)d_in[0];
    const int*   ei    = (const int*)d_in[1];   // [2, N_EDGES]
    const int*   batch = (const int*)d_in[2];   // [N_NODES]
    const float* Wg    = (const float*)d_in[3];
    const float* bg    = (const float*)d_in[4];
    const float* Wa    = (const float*)d_in[5];
    const float* ba    = (const float*)d_in[6];
    float* out = (float*)d_out;

    const int* src = ei;
    const int* dst = ei + N_EDGES;

    // workspace layout (bytes, 256-aligned)
    char* ws = (char*)d_ws;
    unsigned short* xh      = (unsigned short*)(ws);           // 12,800,000
    unsigned int*   pairs   = (unsigned int*)(ws + 12800000);  //  6,400,000
    int*            cstartT = (int*)(ws + 19200000);           //    613,872
    int*            eidx    = (int*)(ws + 19814144);           //  8,007,680
    int*            nbeg    = (int*)(ws + 27821824);           //    400,000
    int*            nend    = (int*)(ws + 28221824);           //    400,000
    float*          denom   = (float*)(ws + 28621824);         //      1,024

    prep_kernel       <<<PREP_BLOCKS, 1024, 0, stream>>>(
        x, xh, src, dst, pairs, cstartT, out, denom);
    compact_kernel    <<<NB2, 512, 0, stream>>>(pairs, cstartT, eidx, nbeg, nend);
    gather_pool_kernel<<<GT_BLOCKS, 256, 0, stream>>>(
        xh, nbeg, nend, eidx, batch, Wg, bg, Wa, ba, out, denom);
    finalize_kernel   <<<(N_GRAPHS * F + 255) / 256, 256, 0, stream>>>(out, denom);
}

// Round 19
// 184.455 us; speedup vs baseline: 3.0434x; 1.0269x over previous
//
#include <hip/hip_runtime.h>

#define N_NODES  100000
#define N_EDGES  1600000
#define N_GRAPHS 256
#define F        64

#define CHUNK    8192
#define NCHUNK   196        // ceil(N_EDGES / CHUNK); last chunk = 2560 edges
#define GBN      128        // nodes per bucket
#define NB2      782        // ceil(N_NODES / GBN)
#define EDGE_CAP 2560       // per-bucket edge cap (mean 2046, sigma 45 -> +11 sigma)

#define CAST_ELEMS   (N_NODES * F / 4)                  // 1,600,000 float4
#define CAST_BLOCKS  ((CAST_ELEMS + 1023) / 1024)       // 1563
#define CPF_BLOCKS   (NB2 + CAST_BLOCKS)                // 2345

__device__ __forceinline__ unsigned short f2bf(float f) {
    unsigned int u = __float_as_uint(f);
    u += 0x7FFFu + ((u >> 16) & 1u);
    return (unsigned short)(u >> 16);
}

// ---------- K1: chunk-local bucket sort only (196 blocks) ----------
__global__ __launch_bounds__(1024) void prep_kernel(
        const int* __restrict__ src, const int* __restrict__ dst,
        unsigned int* __restrict__ pairs, int* __restrict__ cstartT) {
    __shared__ int hist[NB2];
    __shared__ int cur[NB2];
    __shared__ int wsum[16];
    __shared__ unsigned int stage[CHUNK];   // 32 KB
    int tid  = threadIdx.x;
    int c    = blockIdx.x;
    int base = c * CHUNK;
    int m    = min(CHUNK, N_EDGES - base);
    int lane = tid & 63;
    int w    = tid >> 6;

    for (int k = tid; k < NB2; k += 1024) hist[k] = 0;
    __syncthreads();
    for (int e = tid; e < m; e += 1024)
        atomicAdd(&hist[dst[base + e] >> 7], 1);
    __syncthreads();

    // two-level inclusive scan of hist over 1024 threads
    int v = (tid < NB2) ? hist[tid] : 0;
    #pragma unroll
    for (int o = 1; o < 64; o <<= 1) {
        int u = __shfl_up(v, o, 64);
        if (lane >= o) v += u;
    }
    if (lane == 63) wsum[w] = v;
    __syncthreads();
    if (tid < 16) {
        int s = wsum[tid];
        #pragma unroll
        for (int o = 1; o < 16; o <<= 1) {
            int u = __shfl_up(s, o, 64);
            if (tid >= o) s += u;
        }
        wsum[tid] = s;
    }
    __syncthreads();
    if (w > 0) v += wsum[w - 1];

    if (tid < NB2) {
        int excl = v - hist[tid];
        cur[tid] = excl;
        cstartT[tid * NCHUNK + c] = base + excl;
    }
    if (tid == 0) cstartT[NB2 * NCHUNK + c] = base + m;   // sentinel row
    __syncthreads();
    for (int e = tid; e < m; e += 1024) {
        int d = dst[base + e];
        int slot = atomicAdd(&cur[d >> 7], 1);
        stage[slot] = ((unsigned)(d & (GBN - 1)) << 17) | (unsigned)src[base + e];
    }
    __syncthreads();
    for (int e = tid; e < m; e += 1024)
        pairs[base + e] = stage[e];                       // fully coalesced
}

// ---------- K2: fused per-bucket compact + cast(x->bf16) + zero-init ----------
// Blocks [0, NB2): compact (binary-search run copy, 1024 threads).
// Blocks [NB2, ...): streaming cast — overlaps compact's latency stalls.
__global__ __launch_bounds__(1024) void compact_cast_kernel(
        const unsigned int* __restrict__ pairs,
        const int* __restrict__ cstartT,
        int* __restrict__ eidx,     // [NB2 * EDGE_CAP]
        int* __restrict__ nbeg,     // [N_NODES]
        int* __restrict__ nend,     // [N_NODES]
        const float* __restrict__ x,
        unsigned short* __restrict__ xh,
        float* __restrict__ out, float* __restrict__ denom) {
    int tid = threadIdx.x;
    int b   = blockIdx.x;

    if (b >= NB2) {                 // ---- cast section ----
        int ci = b - NB2;
        if (ci == 0) {
            for (int i = tid; i < N_GRAPHS * F; i += 1024) out[i] = 0.f;
            if (tid < N_GRAPHS) denom[tid] = 0.f;
        }
        int i = ci * 1024 + tid;
        if (i < CAST_ELEMS) {
            float4 v = ((const float4*)x)[i];
            ushort4 o;
            o.x = f2bf(v.x); o.y = f2bf(v.y); o.z = f2bf(v.z); o.w = f2bf(v.w);
            ((ushort4*)xh)[i] = o;
        }
        return;
    }

    // ---- compact section ----
    __shared__ int rstart[NCHUNK];
    __shared__ int roff[NCHUNK + 1];
    __shared__ int wsum[16];
    __shared__ unsigned int epairs[EDGE_CAP];   // 10 KB
    __shared__ int ncnt[GBN];
    __shared__ int ncur[GBN];

    int wave  = tid >> 6;
    int lane  = tid & 63;
    int node0 = b * GBN;
    int nn    = min(GBN, N_NODES - node0);
    int gbase = b * EDGE_CAP;

    int myrc = 0;
    if (tid < NCHUNK) {
        int a = cstartT[b * NCHUNK + tid];          // coalesced row
        int n = cstartT[(b + 1) * NCHUNK + tid];
        rstart[tid] = a;
        myrc = n - a;
    }
    __syncthreads();

    // two-level inclusive scan of myrc over 1024 threads
    {
        int v = myrc;
        #pragma unroll
        for (int o = 1; o < 64; o <<= 1) {
            int u = __shfl_up(v, o, 64);
            if (lane >= o) v += u;
        }
        if (lane == 63) wsum[wave] = v;
        __syncthreads();
        if (tid < 16) {
            int s = wsum[tid];
            #pragma unroll
            for (int o = 1; o < 16; o <<= 1) {
                int u = __shfl_up(s, o, 64);
                if (tid >= o) s += u;
            }
            wsum[tid] = s;
        }
        __syncthreads();
        if (wave > 0) v += wsum[wave - 1];
        if (tid < NCHUNK) roff[tid] = v - myrc;
        if (tid == NCHUNK - 1) roff[NCHUNK] = v;
    }
    __syncthreads();
    int E = roff[NCHUNK];

    // all-thread run copy: thread e binary-searches its run (8 LDS steps),
    // then does one independent global load — no serial run chains.
    for (int e = tid; e < E; e += 1024) {
        int lo = 0, hi = NCHUNK - 1;
        while (lo < hi) {
            int mid = (lo + hi + 1) >> 1;
            if (roff[mid] <= e) lo = mid; else hi = mid - 1;
        }
        epairs[e] = pairs[rstart[lo] + (e - roff[lo])];
    }
    __syncthreads();

    // LDS counting sort by dstLocal -> eidx grouped per node
    if (tid < GBN) ncnt[tid] = 0;
    __syncthreads();
    for (int e = tid; e < E; e += 1024)
        atomicAdd(&ncnt[epairs[e] >> 17], 1);
    __syncthreads();
    {
        int mycnt = (tid < GBN) ? ncnt[tid] : 0;
        int v = mycnt;
        #pragma unroll
        for (int o = 1; o < 64; o <<= 1) {
            int u = __shfl_up(v, o, 64);
            if (lane >= o) v += u;
        }
        if (lane == 63) wsum[wave] = v;
        __syncthreads();
        if (tid < 2) {                     // only waves 0,1 hold GBN=128 entries
            int s = wsum[tid];
            int u = __shfl_up(s, 1, 64);
            if (tid >= 1) s += u;
            wsum[tid] = s;
        }
        __syncthreads();
        if (wave == 1) v += wsum[0];
        if (tid < GBN) {
            int excl = v - mycnt;
            ncur[tid] = excl;
            if (tid < nn) {
                nbeg[node0 + tid] = gbase + excl;
                nend[node0 + tid] = gbase + excl + mycnt;
            }
        }
    }
    __syncthreads();
    for (int e = tid; e < E; e += 1024) {
        unsigned int p = epairs[e];
        int slot = atomicAdd(&ncur[p >> 17], 1);
        eidx[gbase + slot] = (int)(p & 0x1FFFFu);   // random within 10 KB window
    }
}

// ---------- K3: fused gather(bf16)+transform+pool (R14/R17-proven body, untouched) ----------
#define NODES_PER_WAVE 25
#define GT_NWAVES  (N_NODES / NODES_PER_WAVE)   // 4000
#define GT_BLOCKS  (GT_NWAVES / 4)              // 1000

__device__ __forceinline__ float bfl(unsigned int u) { return __uint_as_float(u << 16); }
__device__ __forceinline__ float bfh(unsigned int u) { return __uint_as_float(u & 0xFFFF0000u); }

__global__ __launch_bounds__(256) void gather_pool_kernel(
        const unsigned short* __restrict__ xh,
        const int*   __restrict__ nbeg,
        const int*   __restrict__ nend,
        const int*   __restrict__ eidx,
        const int*   __restrict__ batch,
        const float* __restrict__ Wg,   // [64,64] (k, f)
        const float* __restrict__ bg,
        const float* __restrict__ Wa,
        const float* __restrict__ ba,
        float*       __restrict__ out_acc,   // [N_GRAPHS, F]
        float*       __restrict__ denom) {  // [N_GRAPHS]
    int tid  = threadIdx.x;
    int lane = tid & 63;
    int grp  = lane >> 3;   // 0..7: row within an 8-row gather batch
    int c    = lane & 7;    // 16-B chunk (8 bf16) within a row
    int waveId = blockIdx.x * 4 + (tid >> 6);

    int n0   = waveId * NODES_PER_WAVE;     // grid exactly covers N_NODES
    int nEnd = n0 + NODES_PER_WAVE;

    float wcol[F];
    #pragma unroll
    for (int k = 0; k < F; ++k) wcol[k] = Wg[k * F + lane];
    float bgl = bg[lane];
    float wal = Wa[lane];
    float ba0 = ba[0];

    const uint4* xh4 = (const uint4*)xh;     // row = 8 uint4

    int   cur_g = batch[n0];
    float accw  = 0.f;   // per-lane: sum e * h[lane]
    float denw  = 0.f;   // replicated: sum e

    // prefetch state: first-chunk edge indices of the current node
    int pb = nbeg[n0];
    int pe = nend[n0];
    int sl_cur = (pb + lane < pe) ? eidx[pb + lane] : 0;

    for (int n = n0; n < nEnd; ++n) {
        int start = pb, end = pe;
        int sl    = sl_cur;
        if (n + 1 < nEnd) {     // prefetch node n+1 while n's gathers fly
            pb = nbeg[n + 1];
            pe = nend[n + 1];
            sl_cur = (pb + lane < pe) ? eidx[pb + lane] : 0;
        }

        float a0=0.f,a1=0.f,a2=0.f,a3=0.f,a4=0.f,a5=0.f,a6=0.f,a7=0.f;
        // first (almost always only) 64-edge chunk
        {
            int jmax = end - start; if (jmax > 64) jmax = 64;
            for (int j = 0; j < jmax; j += 8) {
                int el = j + grp;
                int s  = __shfl(sl, el, 64);
                if (el < jmax) {
                    uint4 v = xh4[s * 8 + c];   // 16 B/lane, 8 rows per instruction
                    a0 += bfl(v.x); a1 += bfh(v.x);
                    a2 += bfl(v.y); a3 += bfh(v.y);
                    a4 += bfl(v.z); a5 += bfh(v.z);
                    a6 += bfl(v.w); a7 += bfh(v.w);
                }
            }
        }
        // rare extra chunks (deg > 64)
        for (int base = start + 64; base < end; base += 64) {
            int jmax = end - base; if (jmax > 64) jmax = 64;
            int sl2 = (base + lane < end) ? eidx[base + lane] : 0;
            for (int j = 0; j < jmax; j += 8) {
                int el = j + grp;
                int s  = __shfl(sl2, el, 64);
                if (el < jmax) {
                    uint4 v = xh4[s * 8 + c];
                    a0 += bfl(v.x); a1 += bfh(v.x);
                    a2 += bfl(v.y); a3 += bfh(v.y);
                    a4 += bfl(v.z); a5 += bfh(v.z);
                    a6 += bfl(v.w); a7 += bfh(v.w);
                }
            }
        }
        #pragma unroll
        for (int o = 8; o <= 32; o <<= 1) {
            a0 += __shfl_xor(a0, o, 64); a1 += __shfl_xor(a1, o, 64);
            a2 += __shfl_xor(a2, o, 64); a3 += __shfl_xor(a3, o, 64);
            a4 += __shfl_xor(a4, o, 64); a5 += __shfl_xor(a5, o, 64);
            a6 += __shfl_xor(a6, o, 64); a7 += __shfl_xor(a7, o, 64);
        }
        {
            uint4 v = xh4[n * 8 + c];   // self row
            a0 += bfl(v.x); a1 += bfh(v.x);
            a2 += bfl(v.y); a3 += bfh(v.y);
            a4 += bfl(v.z); a5 += bfh(v.z);
            a6 += bfl(v.w); a7 += bfh(v.w);
        }

        float re[8] = {a0,a1,a2,a3,a4,a5,a6,a7};
        float q0=0.f,q1=0.f,q2=0.f,q3=0.f,q4=0.f,q5=0.f,q6=0.f,q7=0.f;
        #pragma unroll
        for (int k = 0; k < F; k += 8) {
            int ln = k >> 3;
            q0 += __int_as_float(__builtin_amdgcn_readlane(__float_as_int(re[0]), ln)) * wcol[k + 0];
            q1 += __int_as_float(__builtin_amdgcn_readlane(__float_as_int(re[1]), ln)) * wcol[k + 1];
            q2 += __int_as_float(__builtin_amdgcn_readlane(__float_as_int(re[2]), ln)) * wcol[k + 2];
            q3 += __int_as_float(__builtin_amdgcn_readlane(__float_as_int(re[3]), ln)) * wcol[k + 3];
            q4 += __int_as_float(__builtin_amdgcn_readlane(__float_as_int(re[4]), ln)) * wcol[k + 4];
            q5 += __int_as_float(__builtin_amdgcn_readlane(__float_as_int(re[5]), ln)) * wcol[k + 5];
            q6 += __int_as_float(__builtin_amdgcn_readlane(__float_as_int(re[6]), ln)) * wcol[k + 6];
            q7 += __int_as_float(__builtin_amdgcn_readlane(__float_as_int(re[7]), ln)) * wcol[k + 7];
        }
        float hv = ((q0 + q1) + (q2 + q3)) + ((q4 + q5) + (q6 + q7)) + bgl;
        hv = hv > 0.f ? hv : 0.f;

        float p = hv * wal;
        #pragma unroll
        for (int o = 32; o > 0; o >>= 1)
            p += __shfl_down(p, o, 64);
        float s = __int_as_float(__builtin_amdgcn_readlane(__float_as_int(p), 0)) + ba0;
        float e = __expf(s);    // unshifted: softmax ratio is shift-invariant

        int g = batch[n];       // wave-uniform
        if (g != cur_g) {
            atomicAdd(&out_acc[cur_g * F + lane], accw);
            if (lane == 0) atomicAdd(&denom[cur_g], denw);
            accw = 0.f; denw = 0.f; cur_g = g;
        }
        accw += e * hv;
        denw += e;
    }
    atomicAdd(&out_acc[cur_g * F + lane], accw);
    if (lane == 0) atomicAdd(&denom[cur_g], denw);
}

// ---------- K4: out /= denom ----------
__global__ __launch_bounds__(256) void finalize_kernel(
        float* __restrict__ out, const float* __restrict__ denom) {
    int i = blockIdx.x * 256 + threadIdx.x;
    if (i >= N_GRAPHS * F) return;
    float d = denom[i >> 6];
    out[i] = (d > 0.f) ? out[i] / d : 0.f;
}

extern "C" void kernel_launch(void* const* d_in, const int* in_sizes, int n_in,
                              void* d_out, int out_size, void* d_ws, size_t ws_size,
                              hipStream_t stream) {
    const float* x     = (const float*)d_in[0];
    const int*   ei    = (const int*)d_in[1];   // [2, N_EDGES]
    const int*   batch = (const int*)d_in[2];   // [N_NODES]
    const float* Wg    = (const float*)d_in[3];
    const float* bg    = (const float*)d_in[4];
    const float* Wa    = (const float*)d_in[5];
    const float* ba    = (const float*)d_in[6];
    float* out = (float*)d_out;

    const int* src = ei;
    const int* dst = ei + N_EDGES;

    // workspace layout (bytes, 256-aligned)
    char* ws = (char*)d_ws;
    unsigned short* xh      = (unsigned short*)(ws);           // 12,800,000
    unsigned int*   pairs   = (unsigned int*)(ws + 12800000);  //  6,400,000
    int*            cstartT = (int*)(ws + 19200000);           //    613,872
    int*            eidx    = (int*)(ws + 19814144);           //  8,007,680
    int*            nbeg    = (int*)(ws + 27821824);           //    400,000
    int*            nend    = (int*)(ws + 28221824);           //    400,000
    float*          denom   = (float*)(ws + 28621824);         //      1,024

    prep_kernel        <<<NCHUNK, 1024, 0, stream>>>(src, dst, pairs, cstartT);
    compact_cast_kernel<<<CPF_BLOCKS, 1024, 0, stream>>>(
        pairs, cstartT, eidx, nbeg, nend, x, xh, out, denom);
    gather_pool_kernel <<<GT_BLOCKS, 256, 0, stream>>>(
        xh, nbeg, nend, eidx, batch, Wg, bg, Wa, ba, out, denom);
    finalize_kernel    <<<(N_GRAPHS * F + 255) / 256, 256, 0, stream>>>(out, denom);
}